// Round 10
// baseline (15120.921 us; speedup 1.0000x reference)
//
#include <hip/hip_runtime.h>
#include <hip/hip_bf16.h>

// 5-layer LSTM, B=64, T=256, H=1024. bf16 MFMA (16x16x32), fp32 state.
// Round 10: r8 structure (barrier-free t-loop, swapped MFMA, lane-local
// epilogue, per-wave u16 flags, sc0/sc1 targeted coherence) with the weight
// store moved to LDS BY CONSTRUCTION:
//  - full 128 KiB fragment-linear slab staged per layer; both x-part and
//    h-part A-frags come from ds_read_b128 (r8 proved this access pattern
//    runs at zero bank conflicts)
//  - kills the scratch-spill the compiler forced on r2/r8/r9 (VGPR weight
//    arrays are unwinnable at HIP source level for this loop shape)

using bf16x8 = __attribute__((ext_vector_type(8))) __bf16;
using f32x4  = __attribute__((ext_vector_type(4))) float;
using u32x2  = __attribute__((ext_vector_type(2))) unsigned;

#define Tn 256
#define Bn 64
#define Hn 1024

#define MFMA16(a, b, c) __builtin_amdgcn_mfma_f32_16x16x32_bf16((a), (b), (c), 0, 0, 0)

// ---------------------------------------------------------------------------
// Wg[l][k][unit] fp32 -> Wperm A-frag-linear bf16.
// Per (l,cb) a 128 KiB slab of 128 frags x 64 lanes x 16 B.
// frag = (p*2+nt)*32 + kt   (p: 0=x,1=h; nt: unit sub-block; kt: K/32 step)
// lane = lhi*16 + c16, c16 = u4*4 + g  (gate g in A-row bits -> D-row j)
// element (gate-col c16 of unit cb*8+nt*4+u4, k = p*1024 + kt*32 + lhi*8 + j)
__global__ void convW(const float* __restrict__ Wi, const float* __restrict__ Wf,
                      const float* __restrict__ Wc, const float* __restrict__ Wo,
                      __bf16* __restrict__ Wperm) {
    int gid = blockIdx.x * 256 + threadIdx.x;      // 5*1024*4*256 = 5,242,880
    int k8   = gid & 255;                          // 8-k chunk: k = k8*8
    int g    = (gid >> 8) & 3;
    int unit = (gid >> 10) & 1023;
    int l    = gid >> 20;
    const float* Wg = (g == 0) ? Wi : (g == 1) ? Wf : (g == 2) ? Wc : Wo;
    const float* src = Wg + ((size_t)l * 2048 + k8 * 8) * 1024 + unit;
    bf16x8 v;
#pragma unroll
    for (int j = 0; j < 8; ++j) v[j] = (__bf16)src[(size_t)j * 1024];
    int cb = unit >> 3, nt = (unit >> 2) & 1, u4 = unit & 3;
    int c16 = u4 * 4 + g;
    int p = k8 >> 7, kt = (k8 >> 2) & 31, lhi = k8 & 3;
    int lane = lhi * 16 + c16;
    int frag = (p * 2 + nt) * 32 + kt;
    size_t dst = ((size_t)(l * 128 + cb) * 128 + frag) * 1024 + lane * 16;
    *(bf16x8*)((char*)Wperm + dst) = v;
}

// x[b][t][k] fp32 -> seq[t][b][k] bf16
__global__ void convX(const float* __restrict__ x, __bf16* __restrict__ seq) {
    int gid = blockIdx.x * 256 + threadIdx.x;      // 2,097,152
    int k8 = gid & 127;
    int b  = (gid >> 7) & 63;
    int t  = gid >> 13;
    const float* src = x + ((size_t)b * Tn + t) * Hn + k8 * 8;
    bf16x8 v;
#pragma unroll
    for (int j = 0; j < 8; ++j) v[j] = (__bf16)src[j];
    *(bf16x8*)(seq + (size_t)gid * 8) = v;
}

// ---------------------------------------------------------------------------
__device__ __forceinline__ void store_coh_u32x2(void* p, u32x2 v) {
    asm volatile("global_store_dwordx2 %0, %1, off sc0 sc1" :: "v"(p), "v"(v) : "memory");
}
__device__ __forceinline__ void store_coh_u16(void* p, unsigned v) {
    asm volatile("global_store_short %0, %1, off sc0 sc1" :: "v"(p), "v"(v) : "memory");
}

// poll own 256-flag group (u16 each), 4 flags/lane, backoff on failure
__device__ __forceinline__ void pollwait(const char* p, unsigned target) {
    while (true) {
        u32x2 v;
        asm volatile("global_load_dwordx2 %0, %1, off sc0 sc1\n\ts_waitcnt vmcnt(0)"
                     : "=&v"(v) : "v"(p) : "memory");
        unsigned w0 = v[0], w1 = v[1];
        bool ok = ((w0 & 0xFFFFu) >= target) && ((w0 >> 16) >= target) &&
                  ((w1 & 0xFFFFu) >= target) && ((w1 >> 16) >= target);
        if (__all((int)ok)) break;
        __builtin_amdgcn_s_sleep(1);
    }
}

// fast gates: v_exp_f32 computes 2^x; v_rcp_f32 ~1ulp
__device__ __forceinline__ float fsigmoid(float z) {
    return __builtin_amdgcn_rcpf(1.f + __builtin_amdgcn_exp2f(-1.44269504089f * z));
}
__device__ __forceinline__ float ftanh(float z) {
    return 1.f - 2.f * __builtin_amdgcn_rcpf(1.f + __builtin_amdgcn_exp2f(2.88539008178f * z));
}

// ---------------------------------------------------------------------------
// Persistent kernel. 256 blocks x 256 threads (4 waves), 1 block/CU.
// Block (rb = bid&1: batch half, cb = bid>>1: units [8cb,8cb+8)).
// Wave w: ms = w&1 (16-row slice), nt = w>>1 (4-unit sub-block).
// Lane (lhi = lane>>4, l15 = lane&15) owns (batch row l15 of its slice,
// unit cb*8+nt*4+lhi); acc[j] = gate j in {i,f,g,o}. Flag groups (rb,ms):
// 256 u16 flags; wave polls/produces only within its group.
// LDS: [0,131072) full weight slab, fragment-linear (x frags 0-63 per nt
// interleave, h frags 64-127).
__global__ __launch_bounds__(256, 2) void lstm_all(
    __bf16* __restrict__ seqA, __bf16* __restrict__ seqB,
    const __bf16* __restrict__ Wperm,
    const float* __restrict__ bip, const float* __restrict__ bfp,
    const float* __restrict__ bcp, const float* __restrict__ bop,
    unsigned short* __restrict__ bar) {
    extern __shared__ char smem[];                 // 128 KiB weight slab

    const int tid  = threadIdx.x;
    const int bid  = blockIdx.x;
    const int rb   = bid & 1;
    const int cb   = bid >> 1;
    const int w    = tid >> 6;
    const int lane = tid & 63;
    const int ms   = w & 1;
    const int nt   = w >> 1;
    const int l15  = lane & 15;
    const int lhi  = lane >> 4;
    const int row  = rb * 32 + ms * 16 + l15;      // batch row (B-frag col)
    const int grp  = rb * 2 + ms;
    const unsigned lane16 = (unsigned)lane << 4;

    unsigned short* myflag = bar + (grp * 128 + cb) * 2 + nt;
    const char* pollp = (const char*)bar + grp * 512 + lane * 8;

    __bf16* inp  = seqA;
    __bf16* outp = seqB;

    for (int l = 0; l < 5; ++l) {
        __syncthreads();                           // old slab no longer read
        pollwait(pollp, (unsigned)(l * Tn));       // prev layer complete (l=0 trivial)
        __builtin_amdgcn_fence(__ATOMIC_ACQUIRE, "agent");   // inv L1/L2

        const char* Wl = (const char*)Wperm + (size_t)(l * 128 + cb) * 131072;
        // stage the full 128 KiB slab (x frags + h frags) into LDS
#pragma unroll
        for (int it = 0; it < 32; ++it) {
            int off = it * 4096 + tid * 16;
            *(bf16x8*)(smem + off) = *(const bf16x8*)(Wl + off);
        }
        const int unit = cb * 8 + nt * 4 + lhi;
        const float bia0 = bip[l * 1024 + unit];
        const float bia1 = bfp[l * 1024 + unit];
        const float bia2 = bcp[l * 1024 + unit];
        const float bia3 = bop[l * 1024 + unit];
        float creg = 0.f;
        __syncthreads();                           // slab staged

        f32x4 acc0 = {}, acc1 = {};
        {   // x-part for t = 0
            const __bf16* xb = inp + (size_t)row * Hn + lhi * 8;
#pragma unroll
            for (int kt = 0; kt < 32; kt += 2) {
                bf16x8 a0 = *(const bf16x8*)(smem + (unsigned)((nt * 32 + kt) << 10) + lane16);
                bf16x8 a1 = *(const bf16x8*)(smem + (unsigned)((nt * 32 + kt + 1) << 10) + lane16);
                bf16x8 b0 = *(const bf16x8*)(xb + kt * 32);
                bf16x8 b1 = *(const bf16x8*)(xb + kt * 32 + 32);
                acc0 = MFMA16(a0, b0, acc0);
                acc1 = MFMA16(a1, b1, acc1);
            }
        }

        for (int t = 0; t < Tn; ++t) {
            if (t > 0) {
                pollwait(pollp, (unsigned)(l * Tn + t));
                // h-part GEMM: B = h[t-1] rows (normal cached, L2 broadcast),
                // A = h-frags from LDS (frag 64..127, conflict-free b128 reads)
                const __bf16* hb = outp + ((size_t)(t - 1) * Bn + row) * Hn + lhi * 8;
#pragma unroll
                for (int kt = 0; kt < 32; kt += 2) {
                    bf16x8 a0 = *(const bf16x8*)(smem + (unsigned)(((2 + nt) * 32 + kt) << 10) + lane16);
                    bf16x8 a1 = *(const bf16x8*)(smem + (unsigned)(((2 + nt) * 32 + kt + 1) << 10) + lane16);
                    bf16x8 b0 = *(const bf16x8*)(hb + kt * 32);
                    bf16x8 b1 = *(const bf16x8*)(hb + kt * 32 + 32);
                    acc0 = MFMA16(a0, b0, acc0);
                    acc1 = MFMA16(a1, b1, acc1);
                }
            }
            // ---- lane-local epilogue: acc[j] = gate j for (row, unit)
            float zi = acc0[0] + acc1[0] + bia0;
            float zf = acc0[1] + acc1[1] + bia1;
            float zg = acc0[2] + acc1[2] + bia2;
            float zo = acc0[3] + acc1[3] + bia3;
            float ii = fsigmoid(zi);
            float ff = fsigmoid(zf);
            float gg = ftanh(zg);
            float oo = fsigmoid(zo);
            creg = creg * ff + ii * gg;
            float hv = oo * ftanh(creg);
            // pack 4 units of one row (lhi 0..3) -> dwordx2 at lanes < 16
            unsigned hb16 = (unsigned)__builtin_bit_cast(unsigned short, (__bf16)hv);
            unsigned d = hb16 | ((unsigned)__shfl_xor((int)hb16, 16) << 16);
            unsigned e = (unsigned)__shfl_xor((int)d, 32);
            if (lane < 16) {
                u32x2 v2 = {d, e};
                store_coh_u32x2(outp + ((size_t)t * Bn + row) * Hn + cb * 8 + nt * 4, v2);
            }
            asm volatile("s_waitcnt vmcnt(0)" ::: "memory");   // h at L3
            if (lane == 0)
                store_coh_u16(myflag, (unsigned)(l * Tn + t + 1));
            // ---- x-part for t+1 (independent of h -> hides flag latency)
            acc0 = (f32x4){}; acc1 = (f32x4){};
            if (t < Tn - 1) {
                const __bf16* xb = inp + ((size_t)(t + 1) * Bn + row) * Hn + lhi * 8;
#pragma unroll
                for (int kt = 0; kt < 32; kt += 2) {
                    bf16x8 a0 = *(const bf16x8*)(smem + (unsigned)((nt * 32 + kt) << 10) + lane16);
                    bf16x8 a1 = *(const bf16x8*)(smem + (unsigned)((nt * 32 + kt + 1) << 10) + lane16);
                    bf16x8 b0 = *(const bf16x8*)(xb + kt * 32);
                    bf16x8 b1 = *(const bf16x8*)(xb + kt * 32 + 32);
                    acc0 = MFMA16(a0, b0, acc0);
                    acc1 = MFMA16(a1, b1, acc1);
                }
            }
        }
        __bf16* tmp = outp; outp = inp; inp = tmp; // ping-pong
    }
}

// ---------------------------------------------------------------------------
// out[b] = dot(h5[T-1][b][:], Wfc) + bfc
__global__ void fc_kernel(const __bf16* __restrict__ seq, const float* __restrict__ Wfc,
                          const float* __restrict__ bfc, float* __restrict__ out) {
    int b = blockIdx.x;
    int tid = threadIdx.x;
    const __bf16* h = seq + ((size_t)(Tn - 1) * Bn + b) * Hn;
    float s = 0.f;
    for (int k = tid; k < Hn; k += 256) s += (float)h[k] * Wfc[k];
#pragma unroll
    for (int off = 32; off > 0; off >>= 1) s += __shfl_down(s, off);
    __shared__ float red[4];
    if ((tid & 63) == 0) red[tid >> 6] = s;
    __syncthreads();
    if (tid == 0) out[b] = red[0] + red[1] + red[2] + red[3] + bfc[0];
}

// ---------------------------------------------------------------------------
extern "C" void kernel_launch(void* const* d_in, const int* in_sizes, int n_in,
                              void* d_out, int out_size, void* d_ws, size_t ws_size,
                              hipStream_t stream) {
    const float* x   = (const float*)d_in[0];
    const float* Wi  = (const float*)d_in[1];
    const float* bi  = (const float*)d_in[2];
    const float* Wf  = (const float*)d_in[3];
    const float* bf  = (const float*)d_in[4];
    const float* Wc  = (const float*)d_in[5];
    const float* bc  = (const float*)d_in[6];
    const float* Wo  = (const float*)d_in[7];
    const float* bo  = (const float*)d_in[8];
    const float* Wfc = (const float*)d_in[9];
    const float* bfc = (const float*)d_in[10];

    char* ws = (char*)d_ws;
    __bf16*         Wperm = (__bf16*)ws;                               // 83,886,080 B
    __bf16*         seqA  = (__bf16*)(ws + 83886080);                  // 33,554,432 B
    __bf16*         seqB  = (__bf16*)(ws + 83886080 + 33554432);       // 33,554,432 B
    unsigned short* bar   = (unsigned short*)(ws + 83886080 + 2 * 33554432); // 2,048 B

    hipFuncSetAttribute((const void*)lstm_all,
                        hipFuncAttributeMaxDynamicSharedMemorySize, 131072);

    hipLaunchKernelGGL(convW, dim3(20480), dim3(256), 0, stream, Wi, Wf, Wc, Wo, Wperm);
    hipLaunchKernelGGL(convX, dim3(8192), dim3(256), 0, stream, x, seqA);
    hipMemsetAsync(bar, 0, 2048, stream);
    hipMemsetAsync(seqB, 0, 33554432, stream);  // sentinel: "didn't run" => exact-ref absmax

    void* args[] = {(void*)&seqA, (void*)&seqB, (void*)&Wperm,
                    (void*)&bi, (void*)&bf, (void*)&bc, (void*)&bo, (void*)&bar};
    hipError_t ce = hipLaunchCooperativeKernel((const void*)lstm_all, dim3(256),
                                               dim3(256), args, 131072, stream);
    if (ce != hipSuccess) {
        // fallback: plain launch. grid (256) <= resident capacity (1 block/CU
        // at 128 KiB LDS), so all blocks co-resident; flag protocol can't
        // deadlock.
        hipLaunchKernelGGL(lstm_all, dim3(256), dim3(256), 131072, stream,
                           seqA, seqB, (const __bf16*)Wperm, bi, bf, bc, bo, bar);
    }

    // after 5 ping-pongs the final hidden sequence is in seqB
    hipLaunchKernelGGL(fc_kernel, dim3(64), dim3(256), 0, stream, seqB, Wfc, bfc,
                       (float*)d_out);
}

// Round 11
// 10374.121 us; speedup vs baseline: 1.4576x; 1.4576x over previous
//
#include <hip/hip_runtime.h>
#include <hip/hip_bf16.h>

// 5-layer LSTM, B=64, T=256, H=1024. bf16 MFMA (16x16x32), fp32 state.
// Round 11: exact r6 skeleton (best measured: 4.57us/hop) + producer-side
// drain-shadow fill:
//  - epilogue waves run x-GEMM(t+1) BETWEEN h-store and vmcnt(0): the x
//    loads/MFMAs execute while h-stores drain to L3, so the flag store
//    (consumer-visible event) moves ~0.3-0.5us earlier in the hop
//  - first poll iteration skips s_sleep
//  - r8's hardened launch (checked coop + fallback + sentinel) retained

using bf16x8 = __attribute__((ext_vector_type(8))) __bf16;
using f32x4  = __attribute__((ext_vector_type(4))) float;
using u32x4  = __attribute__((ext_vector_type(4))) unsigned;

#define Tn 256
#define Bn 64
#define Hn 1024

#define MFMA16(a, b, c) __builtin_amdgcn_mfma_f32_16x16x32_bf16((a), (b), (c), 0, 0, 0)

// ---------------------------------------------------------------------------
// Wg[l][k][unit] fp32 -> Wperm fragment-linear bf16:
// per (l,cb) a 128 KiB slab of 128 fragments x 64 lanes x 16 B.
// frag = ((p*4+kg)*8+kt)*2+nf  (p: 0=x,1=h; kg=K-window; kt; nf=col-half)
// lane = lhi*16 + l15; element (col=nf*16+l15, k=p*1024+kg*256+kt*32+lhi*8+j)
__global__ void convW(const float* __restrict__ Wi, const float* __restrict__ Wf,
                      const float* __restrict__ Wc, const float* __restrict__ Wo,
                      __bf16* __restrict__ Wperm) {
    int gid = blockIdx.x * 256 + threadIdx.x;      // 5*128*32*256 = 5,242,880
    int k8  = gid & 255;                           // 8-k chunk: k = k8*8
    int col = (gid >> 8) & 31;
    int cb  = (gid >> 13) & 127;
    int l   = gid >> 20;
    int g   = col >> 3;
    int uu  = col & 7;
    int unit = cb * 8 + uu;
    const float* Wg = (g == 0) ? Wi : (g == 1) ? Wf : (g == 2) ? Wc : Wo;
    const float* src = Wg + ((size_t)l * 2048 + k8 * 8) * 1024 + unit;
    bf16x8 v;
#pragma unroll
    for (int j = 0; j < 8; ++j) v[j] = (__bf16)src[(size_t)j * 1024];
    int p   = k8 >> 7;
    int kg  = (k8 >> 5) & 3;
    int kt  = (k8 >> 2) & 7;
    int lh  = k8 & 3;
    int nf  = col >> 4;
    int l15 = col & 15;
    int frag = ((p * 4 + kg) * 8 + kt) * 2 + nf;
    int lane = lh * 16 + l15;
    size_t dst = ((size_t)l * 128 + cb) * 131072 + (size_t)frag * 1024 + lane * 16;
    *(bf16x8*)((char*)Wperm + dst) = v;
}

// x[b][t][k] fp32 -> seq[t][b][k] bf16
__global__ void convX(const float* __restrict__ x, __bf16* __restrict__ seq) {
    int gid = blockIdx.x * 256 + threadIdx.x;      // 2,097,152
    int k8 = gid & 127;
    int b  = (gid >> 7) & 63;
    int t  = gid >> 13;
    const float* src = x + ((size_t)b * Tn + t) * Hn + k8 * 8;
    bf16x8 v;
#pragma unroll
    for (int j = 0; j < 8; ++j) v[j] = (__bf16)src[j];
    *(bf16x8*)(seq + (size_t)gid * 8) = v;
}

// ---------------------------------------------------------------------------
__device__ __forceinline__ void store_coh_u32(void* p, unsigned v) {
    asm volatile("global_store_dword %0, %1, off sc0 sc1" :: "v"(p), "v"(v) : "memory");
}
__device__ __forceinline__ void store_coh_u32x4(void* p, u32x4 v) {
    asm volatile("global_store_dwordx4 %0, %1, off sc0 sc1" :: "v"(p), "v"(v) : "memory");
}
__device__ __forceinline__ unsigned load_coh_u32(const void* p) {
    unsigned v;
    asm volatile("global_load_dword %0, %1, off sc0 sc1\n\ts_waitcnt vmcnt(0)"
                 : "=&v"(v) : "v"(p) : "memory");
    return v;
}

// fast gates: v_exp_f32 computes 2^x; v_rcp_f32 ~1ulp
__device__ __forceinline__ float fsigmoid(float z) {
    return __builtin_amdgcn_rcpf(1.f + __builtin_amdgcn_exp2f(-1.44269504089f * z));
}
__device__ __forceinline__ float ftanh(float z) {
    return 1.f - 2.f * __builtin_amdgcn_rcpf(1.f + __builtin_amdgcn_exp2f(2.88539008178f * z));
}

// ---------------------------------------------------------------------------
// Persistent kernel. 256 blocks x 512 threads, 1 block/CU.
// bid: rb = bid&1 (batch half, 32 rows), cb = bid>>1 (8 units = 32 gate cols).
// waves: kg = (tid>>6)&3 (K-window), mg = tid>>8 (16 batch rows).
// Producer flags: wave w (of waves 0-3, rows 8w..8w+8) owns flag dword
// (rb*4+w)*128+cb. Consumer wave (kg,mg) needs rows [16mg,+16) x units
// [256kg,+256) = producer waves {2mg,2mg+1} x cb in [32kg,+32): 64 flags,
// polled 1 dword/lane (two 128B-aligned packed groups).
// LDS: [0,131072) weight slab (fragment-linear); [131072,149504) zp buffer.
__global__ __launch_bounds__(512, 2) void lstm_all(
    __bf16* __restrict__ seqA, __bf16* __restrict__ seqB,
    const __bf16* __restrict__ Wperm,
    const float* __restrict__ bip, const float* __restrict__ bfp,
    const float* __restrict__ bcp, const float* __restrict__ bop,
    unsigned* __restrict__ bar) {
    extern __shared__ char smem[];
    float* zp = (float*)(smem + 131072);           // [4][32][36]

    const int tid  = threadIdx.x;
    const int bid  = blockIdx.x;
    const int rb   = bid & 1;
    const int cb   = bid >> 1;
    const int lane = tid & 63;
    const int kg   = (tid >> 6) & 3;
    const int mg   = tid >> 8;
    const int l15  = lane & 15;
    const int lhi  = lane >> 4;
    const int arow = rb * 32 + mg * 16 + l15;      // batch row for A-frags
    const unsigned lane16 = (unsigned)lane << 4;

    unsigned* myflag = bar + (rb * 4 + (tid >> 6)) * 128 + cb;   // waves 0-3
    const unsigned* pollp = bar + (rb * 4 + 2 * mg + (lane >> 5)) * 128
                                + kg * 32 + (lane & 31);

    __bf16* inp  = seqA;
    __bf16* outp = seqB;

    for (int l = 0; l < 5; ++l) {
        // per-layer acquire: inv L1/L2 so cached reads of the ping-ponged
        // buffers can't hit stale lines from 2 layers ago.
        __builtin_amdgcn_fence(__ATOMIC_ACQUIRE, "agent");

        // ---- stage this layer's 128 KiB weight slab into LDS
        const char* Wl = (const char*)Wperm + ((size_t)l * 128 + cb) * 131072;
#pragma unroll
        for (int it = 0; it < 16; ++it) {
            int off = it * 8192 + tid * 16;
            *(bf16x8*)(smem + off) = *(const bf16x8*)(Wl + off);
        }
        // ---- per-layer epilogue constants + cell state (registers)
        float bia0 = 0.f, bia1 = 0.f, bia2 = 0.f, bia3 = 0.f, creg = 0.f;
        if (tid < 256) {
            int unit = cb * 8 + (tid & 7);
            bia0 = bip[l * 1024 + unit];
            bia1 = bfp[l * 1024 + unit];
            bia2 = bcp[l * 1024 + unit];
            bia3 = bop[l * 1024 + unit];
        }
        __syncthreads();                           // weights staged

        // ---- hold h-part B-fragments in registers (16 frags = 64 VGPR)
        bf16x8 bh[2][8];
#pragma unroll
        for (int nf = 0; nf < 2; ++nf)
#pragma unroll
            for (int kt = 0; kt < 8; ++kt)
                bh[nf][kt] = *(const bf16x8*)(smem +
                    ((unsigned)((((4 + kg) * 8 + kt) * 2 + nf) << 10)) + lane16);

        // ---- x-part GEMM for t = 0
        f32x4 acc0 = {}, acc1 = {};
        {
            const __bf16* ax = inp + (size_t)arow * Hn + kg * 256 + lhi * 8;
#pragma unroll
            for (int kt = 0; kt < 8; ++kt) {
                bf16x8 a  = *(const bf16x8*)(ax + kt * 32);
                bf16x8 b0 = *(const bf16x8*)(smem +
                    ((unsigned)(((kg * 8 + kt) * 2 + 0) << 10)) + lane16);
                bf16x8 b1 = *(const bf16x8*)(smem +
                    ((unsigned)(((kg * 8 + kt) * 2 + 1) << 10)) + lane16);
                acc0 = MFMA16(a, b0, acc0);
                acc1 = MFMA16(a, b1, acc1);
            }
        }

        for (int t = 0; t < Tn; ++t) {
            if (t > 0) {
                // ---- per-wave wait on 64 producer-wave flags (first try
                // without sleep: common path is already-ready)
                unsigned target = (unsigned)(l * Tn + t);
                unsigned v = load_coh_u32(pollp);
                while (!__all((int)(v >= target))) {
                    __builtin_amdgcn_s_sleep(1);
                    v = load_coh_u32(pollp);
                }
                // ---- h-part GEMM for step t: NORMAL CACHED loads (L2 hit
                // for all but the first toucher per XCD), reg-resident B.
                const __bf16* ah = outp + ((size_t)(t - 1) * Bn + arow) * Hn
                                        + kg * 256 + lhi * 8;
                bf16x8 a0 = *(const bf16x8*)(ah);
                bf16x8 a1 = *(const bf16x8*)(ah + 32);
                bf16x8 a2 = *(const bf16x8*)(ah + 64);
                bf16x8 a3 = *(const bf16x8*)(ah + 96);
                bf16x8 a4 = *(const bf16x8*)(ah + 128);
                bf16x8 a5 = *(const bf16x8*)(ah + 160);
                bf16x8 a6 = *(const bf16x8*)(ah + 192);
                bf16x8 a7 = *(const bf16x8*)(ah + 224);
                acc0 = MFMA16(a0, bh[0][0], acc0); acc1 = MFMA16(a0, bh[1][0], acc1);
                acc0 = MFMA16(a1, bh[0][1], acc0); acc1 = MFMA16(a1, bh[1][1], acc1);
                acc0 = MFMA16(a2, bh[0][2], acc0); acc1 = MFMA16(a2, bh[1][2], acc1);
                acc0 = MFMA16(a3, bh[0][3], acc0); acc1 = MFMA16(a3, bh[1][3], acc1);
                acc0 = MFMA16(a4, bh[0][4], acc0); acc1 = MFMA16(a4, bh[1][4], acc1);
                acc0 = MFMA16(a5, bh[0][5], acc0); acc1 = MFMA16(a5, bh[1][5], acc1);
                acc0 = MFMA16(a6, bh[0][6], acc0); acc1 = MFMA16(a6, bh[1][6], acc1);
                acc0 = MFMA16(a7, bh[0][7], acc0); acc1 = MFMA16(a7, bh[1][7], acc1);
            }
            // ---- publish partials (D row = 4*lhi+j, col = 16*nf+l15)
#pragma unroll
            for (int j = 0; j < 4; ++j) {
                int row = kg * 32 + mg * 16 + 4 * lhi + j;
                zp[row * 36 + l15]      = acc0[j];
                zp[row * 36 + 16 + l15] = acc1[j];
            }
            __syncthreads();                       // sync1: zp ready
            // ---- reduce partials (waves 0-3), then release zp via sync2
            float z0 = 0.f, z1 = 0.f, z2 = 0.f, z3 = 0.f;
            if (tid < 256) {
                int uu = tid & 7, eb = tid >> 3;
                z0 = bia0; z1 = bia1; z2 = bia2; z3 = bia3;
#pragma unroll
                for (int k2 = 0; k2 < 4; ++k2) {
                    const float* zr = zp + (k2 * 32 + eb) * 36 + uu;
                    z0 += zr[0]; z1 += zr[8]; z2 += zr[16]; z3 += zr[24];
                }
            }
            __syncthreads();                       // sync2: zp reads done
            // ---- gates + state + h-store, then x-GEMM(t+1) IN THE DRAIN
            // SHADOW, then vmcnt(0) + flag (epilogue waves 0-3)
            acc0 = (f32x4){}; acc1 = (f32x4){};
            if (tid < 256) {
                __builtin_amdgcn_s_setprio(1);
                float ii = fsigmoid(z0);
                float ff = fsigmoid(z1);
                float gg = ftanh(z2);
                float oo = fsigmoid(z3);
                creg = creg * ff + ii * gg;
                float hv = oo * ftanh(creg);
                // pack 8 units of one batch row into one dwordx4 (shfl tree)
                unsigned hb = (unsigned)__builtin_bit_cast(unsigned short, (__bf16)hv);
                unsigned d  = hb | ((unsigned)__shfl_xor((int)hb, 1) << 16);
                unsigned d2 = (unsigned)__shfl_xor((int)d, 2);
                unsigned e0 = (unsigned)__shfl_xor((int)d, 4);
                unsigned e1 = (unsigned)__shfl_xor((int)d2, 4);
                if ((lane & 7) == 0) {
                    int eb = tid >> 3;
                    u32x4 v4 = {d, d2, e0, e1};
                    store_coh_u32x4(outp + (((size_t)t * Bn + rb * 32 + eb) * Hn
                                            + cb * 8), v4);
                }
                // x-part for t+1 while the h-stores drain (loads+MFMAs are
                // independent of the stores; vmcnt(0) below covers both)
                if (t < Tn - 1) {
                    const __bf16* ax = inp + ((size_t)(t + 1) * Bn + arow) * Hn
                                           + kg * 256 + lhi * 8;
#pragma unroll
                    for (int kt = 0; kt < 8; ++kt) {
                        bf16x8 a  = *(const bf16x8*)(ax + kt * 32);
                        bf16x8 b0 = *(const bf16x8*)(smem +
                            ((unsigned)(((kg * 8 + kt) * 2 + 0) << 10)) + lane16);
                        bf16x8 b1 = *(const bf16x8*)(smem +
                            ((unsigned)(((kg * 8 + kt) * 2 + 1) << 10)) + lane16);
                        acc0 = MFMA16(a, b0, acc0);
                        acc1 = MFMA16(a, b1, acc1);
                    }
                }
                asm volatile("s_waitcnt vmcnt(0)" ::: "memory");  // h at L3
                if ((tid & 63) == 0)
                    store_coh_u32(myflag, (unsigned)(l * Tn + t + 1));
                __builtin_amdgcn_s_setprio(0);
            } else {
                // waves 4-7: no epilogue; x-part for t+1 directly
                if (t < Tn - 1) {
                    const __bf16* ax = inp + ((size_t)(t + 1) * Bn + arow) * Hn
                                           + kg * 256 + lhi * 8;
#pragma unroll
                    for (int kt = 0; kt < 8; ++kt) {
                        bf16x8 a  = *(const bf16x8*)(ax + kt * 32);
                        bf16x8 b0 = *(const bf16x8*)(smem +
                            ((unsigned)(((kg * 8 + kt) * 2 + 0) << 10)) + lane16);
                        bf16x8 b1 = *(const bf16x8*)(smem +
                            ((unsigned)(((kg * 8 + kt) * 2 + 1) << 10)) + lane16);
                        acc0 = MFMA16(a, b0, acc0);
                        acc1 = MFMA16(a, b1, acc1);
                    }
                }
            }
        }
        __bf16* tmp = outp; outp = inp; inp = tmp; // ping-pong
    }
}

// ---------------------------------------------------------------------------
// out[b] = dot(h5[T-1][b][:], Wfc) + bfc
__global__ void fc_kernel(const __bf16* __restrict__ seq, const float* __restrict__ Wfc,
                          const float* __restrict__ bfc, float* __restrict__ out) {
    int b = blockIdx.x;
    int tid = threadIdx.x;
    const __bf16* h = seq + ((size_t)(Tn - 1) * Bn + b) * Hn;
    float s = 0.f;
    for (int k = tid; k < Hn; k += 256) s += (float)h[k] * Wfc[k];
#pragma unroll
    for (int off = 32; off > 0; off >>= 1) s += __shfl_down(s, off);
    __shared__ float red[4];
    if ((tid & 63) == 0) red[tid >> 6] = s;
    __syncthreads();
    if (tid == 0) out[b] = red[0] + red[1] + red[2] + red[3] + bfc[0];
}

// ---------------------------------------------------------------------------
extern "C" void kernel_launch(void* const* d_in, const int* in_sizes, int n_in,
                              void* d_out, int out_size, void* d_ws, size_t ws_size,
                              hipStream_t stream) {
    const float* x   = (const float*)d_in[0];
    const float* Wi  = (const float*)d_in[1];
    const float* bi  = (const float*)d_in[2];
    const float* Wf  = (const float*)d_in[3];
    const float* bf  = (const float*)d_in[4];
    const float* Wc  = (const float*)d_in[5];
    const float* bc  = (const float*)d_in[6];
    const float* Wo  = (const float*)d_in[7];
    const float* bo  = (const float*)d_in[8];
    const float* Wfc = (const float*)d_in[9];
    const float* bfc = (const float*)d_in[10];

    char* ws = (char*)d_ws;
    __bf16*   Wperm = (__bf16*)ws;                                 // 83,886,080 B
    __bf16*   seqA  = (__bf16*)(ws + 83886080);                    // 33,554,432 B
    __bf16*   seqB  = (__bf16*)(ws + 83886080 + 33554432);         // 33,554,432 B
    unsigned* bar   = (unsigned*)(ws + 83886080 + 2 * 33554432);   //      4,096 B

    hipFuncSetAttribute((const void*)lstm_all,
                        hipFuncAttributeMaxDynamicSharedMemorySize, 149504);

    hipLaunchKernelGGL(convW, dim3(20480), dim3(256), 0, stream, Wi, Wf, Wc, Wo, Wperm);
    hipLaunchKernelGGL(convX, dim3(8192), dim3(256), 0, stream, x, seqA);
    hipMemsetAsync(bar, 0, 4096, stream);
    hipMemsetAsync(seqB, 0, 33554432, stream);  // sentinel: "didn't run" => exact-ref absmax

    void* args[] = {(void*)&seqA, (void*)&seqB, (void*)&Wperm,
                    (void*)&bi, (void*)&bf, (void*)&bc, (void*)&bo, (void*)&bar};
    hipError_t ce = hipLaunchCooperativeKernel((const void*)lstm_all, dim3(256),
                                               dim3(512), args, 149504, stream);
    if (ce != hipSuccess) {
        // fallback: plain launch. grid (256) <= resident capacity (1 block/CU
        // at 149,504 B LDS), so all blocks co-resident; flag protocol can't
        // deadlock.
        hipLaunchKernelGGL(lstm_all, dim3(256), dim3(512), 149504, stream,
                           seqA, seqB, (const __bf16*)Wperm, bi, bf, bc, bo, bar);
    }

    // after 5 ping-pongs the final hidden sequence is in seqB
    hipLaunchKernelGGL(fc_kernel, dim3(64), dim3(256), 0, stream, seqB, Wfc, bfc,
                       (float*)d_out);
}